// Round 16
// baseline (169.531 us; speedup 1.0000x reference)
//
#include <hip/hip_runtime.h>
#include <math.h>

#define NN 50000
#define NE 800000
#define HD 128
#define NG 32
#define GN_EPS 1e-5f
#define NSH 8

// radix CSR build params (NBLK_R=800: rscatter needs TLP -- R15's 250 regressed)
#define NBLK_R 800
#define CH_R   1000             // 800*1000 = NE
#define NBUCK  196              // dst>>8 buckets
#define NBB    (NBUCK * NBLK_R) // 156800
#define NCHS   ((NBB + 255) / 256)  // 613
#define DCAP   8192
#define PREP_BLKS 3125          // NN*16/256

// gather src-window passes: per-pass x working set = 12500*256B = 3.2MB -> fits
// one XCD's 4MB L2 (R15 profile: monolithic gather missed 60%, FETCH 123MB)
#define GP 4
#define GW (NN / GP)            // 12500

typedef __bf16 v8bf __attribute__((ext_vector_type(8)));
typedef float f32x4 __attribute__((ext_vector_type(4)));

// ---- ws layout (4-byte element offsets) ----
#define ROWPTR_OFF 0            // 50001 ints
#define BB_OFF     50016        // 156800 ints
#define CS_OFF     206816       // 1024 ints (613 used)
#define GSUMS_OFF  207840       // 8*4096 floats
#define GSQS_OFF   240608       // 8*4096 floats
#define GCNTS_OFF  273376       // 256 floats
#define MEAN_OFF   273632       // 4096 floats
#define RSTD_OFF   277728       // 4096 floats
#define SRCS_OFF   281824       // 800000 ushorts
#define PSRC_OFF   681824       // 800000 ushorts
#define PDLOW_OFF  1081824      // 800000 uchars
#define WPACK_OFF  1281824      // 32768 ushorts
#define ABUF_OFF   1298208      // 50000*256 ushorts (bf16 [agg|x])
#define OBF_OFF    7698208      // 50000*128 ushorts (bf16 pre-norm out)
#define MEMSET_INTS (32768 + 32768 + 256)   // gsumS|gsqS|gcntS from GSUMS_OFF

__device__ __forceinline__ unsigned short f2bf(float f) {
  unsigned int u = __float_as_uint(f);
  u = (u + 0x7fffu + ((u >> 16) & 1u)) >> 16;   // RNE
  return (unsigned short)u;
}
__device__ __forceinline__ float bf_lo(unsigned int u) { return __uint_as_float(u << 16); }
__device__ __forceinline__ float bf_hi(unsigned int u) { return __uint_as_float(u & 0xffff0000u); }

// fused: [blocks 0..3124] zero stats + pack W + x f32->bf16 into Abuf x-half
//        [blocks 3125..3924] radix histogram of dst>>8 (int4-vectorized)
__global__ __launch_bounds__(256) void prep_rhist_k(const float* __restrict__ x,
    const float* __restrict__ Wl, const float* __restrict__ Wr,
    unsigned short* __restrict__ Abuf, unsigned short* __restrict__ wp,
    int* __restrict__ zbase, const int* __restrict__ ei, int* __restrict__ bb) {
  __shared__ int h[NBUCK];
  int tid = threadIdx.x;
  if (blockIdx.x < PREP_BLKS) {
    int i = blockIdx.x * 256 + tid;
    if (i < MEMSET_INTS) zbase[i] = 0;
    if (i < 32768) {
      int e = i & 7, lane = (i >> 3) & 63, nt = (i >> 9) & 7, ks = i >> 12;
      int k = ks * 32 + (lane >> 4) * 8 + e;
      int c = nt * 16 + (lane & 15);
      float v = (k < HD) ? Wl[k * HD + c] : Wr[(k - HD) * HD + c];
      wp[i] = f2bf(v);
    }
    if (i < NN * 16) {
      int n = i >> 4, seg = i & 15;
      const float* src = x + (size_t)n * HD + seg * 8;
      float4 v0 = *(const float4*)(src);
      float4 v1 = *(const float4*)(src + 4);
      uint4 o;
      o.x = (unsigned)f2bf(v0.x) | ((unsigned)f2bf(v0.y) << 16);
      o.y = (unsigned)f2bf(v0.z) | ((unsigned)f2bf(v0.w) << 16);
      o.z = (unsigned)f2bf(v1.x) | ((unsigned)f2bf(v1.y) << 16);
      o.w = (unsigned)f2bf(v1.z) | ((unsigned)f2bf(v1.w) << 16);
      *(uint4*)(Abuf + (size_t)n * 256 + 128 + seg * 8) = o;
    }
  } else {
    int b = blockIdx.x - PREP_BLKS;
    for (int i = tid; i < NBUCK; i += 256) h[i] = 0;
    __syncthreads();
    int base = b * CH_R;
    if (tid < CH_R / 4) {
      int4 d = *(const int4*)(ei + NE + base + tid * 4);
      atomicAdd(&h[d.x >> 8], 1);
      atomicAdd(&h[d.y >> 8], 1);
      atomicAdd(&h[d.z >> 8], 1);
      atomicAdd(&h[d.w >> 8], 1);
    }
    __syncthreads();
    for (int i = tid; i < NBUCK; i += 256) bb[i * NBLK_R + b] = h[i];
  }
}

// B1: chunk sums of bb (613 chunks of 256)
__global__ __launch_bounds__(256) void csum_k(const int* __restrict__ bb,
                                              int* __restrict__ cs) {
  __shared__ int red[4];
  int i = blockIdx.x * 256 + threadIdx.x;
  int v = (i < NBB) ? bb[i] : 0;
#pragma unroll
  for (int off = 32; off; off >>= 1) v += __shfl_down(v, off, 64);
  if ((threadIdx.x & 63) == 0) red[threadIdx.x >> 6] = v;
  __syncthreads();
  if (threadIdx.x == 0) cs[blockIdx.x] = red[0] + red[1] + red[2] + red[3];
}

// B2 (fused scan): 1024-thread blocks; each scans the 613 chunk sums in LDS
// (chunk prefix = sb[4*blk-1]) + in-block scan of its 1024 bb values.
__global__ __launch_bounds__(1024) void cfill_k(int* __restrict__ bb,
                                                const int* __restrict__ cs) {
  __shared__ int sb[1024];
  __shared__ int s[1024];
  int t = threadIdx.x;
  sb[t] = (t < NCHS) ? cs[t] : 0;
  int i = blockIdx.x * 1024 + t;
  int c = (i < NBB) ? bb[i] : 0;
  s[t] = c;
  __syncthreads();
  for (int off = 1; off < 1024; off <<= 1) {
    int u1 = (t >= off) ? sb[t - off] : 0;
    int u2 = (t >= off) ? s[t - off] : 0;
    __syncthreads();
    sb[t] += u1;
    s[t] += u2;
    __syncthreads();
  }
  int chunkpre = (blockIdx.x == 0) ? 0 : sb[blockIdx.x * 4 - 1];
  if (i < NBB) bb[i] = chunkpre + s[t] - c;
}

// C: scatter pass-1 (int4 ei reads, LDS cursors, no global atomics, 800 blocks)
__global__ __launch_bounds__(256) void rscatter_k(const int* __restrict__ ei,
    const int* __restrict__ bb, unsigned short* __restrict__ psrc,
    unsigned char* __restrict__ pdlow) {
  __shared__ int cur[NBUCK];
  int tid = threadIdx.x, b = blockIdx.x;
  for (int i = tid; i < NBUCK; i += 256) cur[i] = bb[i * NBLK_R + b];
  __syncthreads();
  int base = b * CH_R;
  if (tid < CH_R / 4) {
    int4 s4 = *(const int4*)(ei + base + tid * 4);
    int4 d4 = *(const int4*)(ei + NE + base + tid * 4);
    int p;
    p = atomicAdd(&cur[d4.x >> 8], 1); psrc[p] = (unsigned short)s4.x; pdlow[p] = (unsigned char)(d4.x & 255);
    p = atomicAdd(&cur[d4.y >> 8], 1); psrc[p] = (unsigned short)s4.y; pdlow[p] = (unsigned char)(d4.y & 255);
    p = atomicAdd(&cur[d4.z >> 8], 1); psrc[p] = (unsigned short)s4.z; pdlow[p] = (unsigned char)(d4.z & 255);
    p = atomicAdd(&cur[d4.w >> 8], 1); psrc[p] = (unsigned short)s4.w; pdlow[p] = (unsigned char)(d4.w & 255);
  }
}

// D: pass-2 inside one bucket: LDS hist256 + scan + place; coalesced srcs out
__global__ __launch_bounds__(256) void rfinal_k(const int* __restrict__ bb,
    const unsigned short* __restrict__ psrc, const unsigned char* __restrict__ pdlow,
    unsigned short* __restrict__ srcs, int* __restrict__ rowptr) {
  __shared__ unsigned short ssrc[DCAP];
  __shared__ unsigned short sout[DCAP];
  __shared__ unsigned char sdl[DCAP];
  __shared__ int h2[256], scn[256], cur2[256];
  int tid = threadIdx.x, k = blockIdx.x;
  int segB = bb[k * NBLK_R];
  int segE = (k == NBUCK - 1) ? NE : bb[(k + 1) * NBLK_R];
  int cnt = segE - segB;
  for (int j = tid; j < cnt; j += 256) {
    ssrc[j] = psrc[segB + j];
    sdl[j] = pdlow[segB + j];
  }
  h2[tid] = 0;
  __syncthreads();
  for (int j = tid; j < cnt; j += 256) atomicAdd(&h2[sdl[j]], 1);
  __syncthreads();
  scn[tid] = h2[tid];
  __syncthreads();
#pragma unroll
  for (int off = 1; off < 256; off <<= 1) {
    int u = (tid >= off) ? scn[tid - off] : 0;
    __syncthreads();
    scn[tid] += u;
    __syncthreads();
  }
  int excl = scn[tid] - h2[tid];
  cur2[tid] = excl;
  int dst = k * 256 + tid;
  if (dst < NN) rowptr[dst] = segB + excl;
  if (dst == NN - 1) rowptr[NN] = NE;
  __syncthreads();
  for (int j = tid; j < cnt; j += 256) {
    int p = atomicAdd(&cur2[sdl[j]], 1);
    sout[p] = ssrc[j];
  }
  __syncthreads();
  for (int j = tid; j < cnt; j += 256) srcs[segB + j] = sout[j];
}

// gather with GP src-window passes: each pass touches a 3.2MB slice of x ->
// L2-resident per XCD. Branch is uniform per 16-lane group (shared srcs[i]).
__global__ __launch_bounds__(256) void gather_k(const int* __restrict__ rowptr,
    const unsigned short* __restrict__ srcs, unsigned short* Abuf) {
  int t = blockIdx.x * 256 + threadIdx.x;
  int n = t >> 4, q = t & 15;
  if (n >= NN) return;
  int b = rowptr[n], e = rowptr[n + 1];
  float a0=0,a1=0,a2=0,a3=0,a4=0,a5=0,a6=0,a7=0;
#pragma unroll 1
  for (int p = 0; p < GP; ++p) {
    int lo = p * GW, hi = lo + GW;
    for (int i = b; i < e; ++i) {
      int s0 = srcs[i];
      if (s0 >= lo && s0 < hi) {
        uint4 v0 = *(const uint4*)(Abuf + (size_t)s0 * 256 + 128 + q * 8);
        a0 += bf_lo(v0.x); a1 += bf_hi(v0.x);
        a2 += bf_lo(v0.y); a3 += bf_hi(v0.y);
        a4 += bf_lo(v0.z); a5 += bf_hi(v0.z);
        a6 += bf_lo(v0.w); a7 += bf_hi(v0.w);
      }
    }
  }
  float inv = 1.0f / fmaxf((float)(e - b), 1.0f);
  uint4 o;
  o.x = (unsigned)f2bf(a0 * inv) | ((unsigned)f2bf(a1 * inv) << 16);
  o.y = (unsigned)f2bf(a2 * inv) | ((unsigned)f2bf(a3 * inv) << 16);
  o.z = (unsigned)f2bf(a4 * inv) | ((unsigned)f2bf(a5 * inv) << 16);
  o.w = (unsigned)f2bf(a6 * inv) | ((unsigned)f2bf(a7 * inv) << 16);
  *(uint4*)(Abuf + (size_t)n * 256 + q * 8) = o;
}

// MFMA GEMM + fused GraphNorm stats (per-XCD-shard partials); bf16 obf out.
__global__ __launch_bounds__(256) void gemm_k(const unsigned short* __restrict__ Abuf,
    const unsigned short* __restrict__ wp, const float* __restrict__ bl,
    const int* __restrict__ batch, unsigned short* __restrict__ obf,
    float* __restrict__ gsumS, float* __restrict__ gsqS,
    float* __restrict__ gcntS) {
  __shared__ float lsum[16][136];
  __shared__ float lsq[16][136];
  __shared__ unsigned char ridx[64];
  __shared__ int sg0, snrun;
  int tid = threadIdx.x;
  int base0 = blockIdx.x * 64;
  int nvalid = min(64, NN - base0);
  if (tid == 0) {
    int g0 = batch[base0];
    sg0 = g0;
    snrun = batch[base0 + nvalid - 1] - g0 + 1;
  }
  __syncthreads();
  if (tid < 64)
    ridx[tid] = (tid < nvalid) ? (unsigned char)(batch[base0 + tid] - sg0)
                               : (unsigned char)0;
  __syncthreads();

  int shard = blockIdx.x & 7;
  float* gs = gsumS + shard * (NG * HD);
  float* gq = gsqS + shard * (NG * HD);
  float* gc = gcntS + shard * NG;

  int wave = tid >> 6;
  int lane = tid & 63;
  int base = base0 + wave * 16;
  int row = lane & 15, kg = lane >> 4;
  int node = base + row;
  if (node > NN - 1) node = NN - 1;
  const unsigned short* arow = Abuf + (size_t)node * 256 + kg * 8;
  f32x4 acc[8] = {};
#pragma unroll
  for (int ks = 0; ks < 8; ++ks) {
    v8bf a = __builtin_bit_cast(v8bf, *(const uint4*)(arow + ks * 32));
    const unsigned short* wrow = wp + ks * 4096 + lane * 8;
#pragma unroll
    for (int nt = 0; nt < 8; ++nt) {
      v8bf b = __builtin_bit_cast(v8bf, *(const uint4*)(wrow + nt * 512));
      acc[nt] = __builtin_amdgcn_mfma_f32_16x16x32_bf16(a, b, acc[nt], 0, 0, 0);
    }
  }
  int c0 = lane & 15;
  float bv[8];
#pragma unroll
  for (int nt = 0; nt < 8; ++nt) bv[nt] = bl[nt * 16 + c0];

  if (snrun == 1) {
    float ps0[8] = {}, pq0[8] = {};
#pragma unroll
    for (int j = 0; j < 4; ++j) {
      int n = base0 + wave * 16 + kg * 4 + j;
      if (n >= NN) break;
      unsigned short* orow = obf + (size_t)n * HD;
#pragma unroll
      for (int nt = 0; nt < 8; ++nt) {
        float v = acc[nt][j] + bv[nt];
        orow[nt * 16 + c0] = f2bf(v);
        ps0[nt] += v;
        pq0[nt] += v * v;
      }
    }
    int r = wave * 4 + kg;
#pragma unroll
    for (int nt = 0; nt < 8; ++nt) {
      lsum[r][nt * 16 + c0] = ps0[nt];
      lsq[r][nt * 16 + c0] = pq0[nt];
    }
    __syncthreads();
    if (tid < HD) {
      float s = 0.0f, q = 0.0f;
#pragma unroll
      for (int r2 = 0; r2 < 16; ++r2) { s += lsum[r2][tid]; q += lsq[r2][tid]; }
      atomicAdd(gs + sg0 * HD + tid, s);
      atomicAdd(gq + sg0 * HD + tid, q);
    }
    if (tid == 0) atomicAdd(gc + sg0, (float)nvalid);
  } else if (snrun == 2) {
    float ps0[8] = {}, pq0[8] = {}, ps1[8] = {}, pq1[8] = {};
#pragma unroll
    for (int j = 0; j < 4; ++j) {
      int rb = wave * 16 + kg * 4 + j;
      int n = base0 + rb;
      if (n >= NN) break;
      unsigned short* orow = obf + (size_t)n * HD;
      bool b1 = (ridx[rb] != 0);
#pragma unroll
      for (int nt = 0; nt < 8; ++nt) {
        float v = acc[nt][j] + bv[nt];
        orow[nt * 16 + c0] = f2bf(v);
        if (b1) { ps1[nt] += v; pq1[nt] += v * v; }
        else    { ps0[nt] += v; pq0[nt] += v * v; }
      }
    }
    int r = wave * 4 + kg;
#pragma unroll
    for (int nt = 0; nt < 8; ++nt) {
      lsum[r][nt * 16 + c0] = ps0[nt];
      lsq[r][nt * 16 + c0] = pq0[nt];
    }
    __syncthreads();
    if (tid < HD) {
      float s = 0.0f, q = 0.0f;
#pragma unroll
      for (int r2 = 0; r2 < 16; ++r2) { s += lsum[r2][tid]; q += lsq[r2][tid]; }
      atomicAdd(gs + sg0 * HD + tid, s);
      atomicAdd(gq + sg0 * HD + tid, q);
    }
    __syncthreads();
#pragma unroll
    for (int nt = 0; nt < 8; ++nt) {
      lsum[r][nt * 16 + c0] = ps1[nt];
      lsq[r][nt * 16 + c0] = pq1[nt];
    }
    __syncthreads();
    if (tid < HD) {
      float s = 0.0f, q = 0.0f;
#pragma unroll
      for (int r2 = 0; r2 < 16; ++r2) { s += lsum[r2][tid]; q += lsq[r2][tid]; }
      atomicAdd(gs + (sg0 + 1) * HD + tid, s);
      atomicAdd(gq + (sg0 + 1) * HD + tid, q);
    }
    if (tid == 0) {
      int n0 = 0;
      for (int r2 = 0; r2 < nvalid; ++r2) n0 += (ridx[r2] == 0);
      atomicAdd(gc + sg0, (float)n0);
      atomicAdd(gc + sg0 + 1, (float)(nvalid - n0));
    }
  } else {
#pragma unroll
    for (int j = 0; j < 4; ++j) {
      int rb = wave * 16 + kg * 4 + j;
      int n = base0 + rb;
      if (n >= NN) break;
      unsigned short* orow = obf + (size_t)n * HD;
      int g = sg0 + ridx[rb];
#pragma unroll
      for (int nt = 0; nt < 8; ++nt) {
        float v = acc[nt][j] + bv[nt];
        orow[nt * 16 + c0] = f2bf(v);
        atomicAdd(gs + g * HD + nt * 16 + c0, v);
        atomicAdd(gq + g * HD + nt * 16 + c0, v * v);
      }
    }
    if (tid < nvalid) atomicAdd(gc + batch[base0 + tid], 1.0f);
  }
}

// reduce 8 shard partials -> mean, rstd
__global__ __launch_bounds__(256) void finalize_k(const float* __restrict__ gsumS,
    const float* __restrict__ gsqS, const float* __restrict__ gcntS,
    const float* __restrict__ alpha, float* __restrict__ mean,
    float* __restrict__ rstd) {
  int i = blockIdx.x * 256 + threadIdx.x;
  if (i >= NG * HD) return;
  int g = i >> 7, d = i & 127;
  float s = 0.0f, q = 0.0f, cnt = 0.0f;
#pragma unroll
  for (int sh = 0; sh < NSH; ++sh) {
    s += gsumS[sh * (NG * HD) + i];
    q += gsqS[sh * (NG * HD) + i];
    cnt += gcntS[sh * NG + g];
  }
  cnt = fmaxf(cnt, 1.0f);
  float mu = s / cnt;
  float a = alpha[d];
  float var = q / cnt - mu * mu * (2.0f * a - a * a);
  mean[i] = mu;
  rstd[i] = rsqrtf(fmaxf(var, 0.0f) + GN_EPS);
}

// norm + GELU + residual: reads bf16 obf + f32 x, writes f32 d_out
__global__ __launch_bounds__(256) void final_k(const unsigned short* __restrict__ obf,
    float* __restrict__ out, const float* __restrict__ x,
    const int* __restrict__ batch, const float* __restrict__ mean,
    const float* __restrict__ rstd, const float* __restrict__ alpha,
    const float* __restrict__ gw, const float* __restrict__ gb) {
  size_t i = ((size_t)blockIdx.x * 256 + threadIdx.x) * 4;
  if (i >= (size_t)NN * HD) return;
  int n = (int)(i >> 7);
  int d = (int)(i & 127);
  int g = batch[n];
  uint2 ov = *(const uint2*)(obf + i);
  float4 xv = *(const float4*)(x + i);
  float4 al = *(const float4*)(alpha + d);
  float4 w  = *(const float4*)(gw + d);
  float4 b  = *(const float4*)(gb + d);
  float4 mn = *(const float4*)(mean + (size_t)g * HD + d);
  float4 rs = *(const float4*)(rstd + (size_t)g * HD + d);
  float vv[4] = {bf_lo(ov.x), bf_hi(ov.x), bf_lo(ov.y), bf_hi(ov.y)};
  float xx[4] = {xv.x, xv.y, xv.z, xv.w};
  float aa[4] = {al.x, al.y, al.z, al.w};
  float ww[4] = {w.x, w.y, w.z, w.w};
  float bb2[4] = {b.x, b.y, b.z, b.w};
  float mm[4] = {mn.x, mn.y, mn.z, mn.w};
  float rr[4] = {rs.x, rs.y, rs.z, rs.w};
  float r[4];
#pragma unroll
  for (int c = 0; c < 4; ++c) {
    float sub = vv[c] - aa[c] * mm[c];
    float nm  = ww[c] * sub * rr[c] + bb2[c];
    float ge  = 0.5f * nm * (1.0f + erff(nm * 0.70710678118654752f));
    r[c] = ge + xx[c];
  }
  float4 res = {r[0], r[1], r[2], r[3]};
  *(float4*)(out + i) = res;
}

extern "C" void kernel_launch(void* const* d_in, const int* in_sizes, int n_in,
                              void* d_out, int out_size, void* d_ws, size_t ws_size,
                              hipStream_t stream) {
  const float* x     = (const float*)d_in[0];
  const int*   ei    = (const int*)d_in[1];
  const int*   batch = (const int*)d_in[2];
  const float* Wl    = (const float*)d_in[3];
  const float* bl    = (const float*)d_in[4];
  const float* Wr    = (const float*)d_in[5];
  const float* gw    = (const float*)d_in[6];
  const float* gb    = (const float*)d_in[7];
  const float* alpha = (const float*)d_in[8];

  float* out = (float*)d_out;
  int*   wsi = (int*)d_ws;
  float* wsf = (float*)d_ws;
  int* rowptr = wsi + ROWPTR_OFF;
  int* bb     = wsi + BB_OFF;
  int* cs     = wsi + CS_OFF;
  float* gsumS = wsf + GSUMS_OFF;
  float* gsqS  = wsf + GSQS_OFF;
  float* gcntS = wsf + GCNTS_OFF;
  float* mean  = wsf + MEAN_OFF;
  float* rstd  = wsf + RSTD_OFF;
  unsigned short* srcs  = (unsigned short*)(wsi + SRCS_OFF);
  unsigned short* psrc  = (unsigned short*)(wsi + PSRC_OFF);
  unsigned char*  pdlow = (unsigned char*)(wsi + PDLOW_OFF);
  unsigned short* wpack = (unsigned short*)(wsi + WPACK_OFF);
  unsigned short* Abuf  = (unsigned short*)(wsi + ABUF_OFF);
  unsigned short* obf   = (unsigned short*)(wsi + OBF_OFF);

  prep_rhist_k<<<PREP_BLKS + NBLK_R, 256, 0, stream>>>(
      x, Wl, Wr, Abuf, wpack, (int*)(wsf + GSUMS_OFF), ei, bb);

  csum_k<<<NCHS, 256, 0, stream>>>(bb, cs);
  cfill_k<<<(NBB + 1023) / 1024, 1024, 0, stream>>>(bb, cs);
  rscatter_k<<<NBLK_R, 256, 0, stream>>>(ei, bb, psrc, pdlow);
  rfinal_k<<<NBUCK, 256, 0, stream>>>(bb, psrc, pdlow, srcs, rowptr);

  gather_k<<<(NN * 16 + 255) / 256, 256, 0, stream>>>(rowptr, srcs, Abuf);

  gemm_k<<<(NN + 63) / 64, 256, 0, stream>>>(Abuf, wpack, bl, batch, obf,
                                             gsumS, gsqS, gcntS);

  finalize_k<<<16, 256, 0, stream>>>(gsumS, gsqS, gcntS, alpha, mean, rstd);

  final_k<<<(NN * HD / 4 + 255) / 256, 256, 0, stream>>>(
      obf, out, x, batch, mean, rstd, alpha, gw, gb);
}

// Round 18
// 97.424 us; speedup vs baseline: 1.7401x; 1.7401x over previous
//
#include <hip/hip_runtime.h>
#include <math.h>

#define NN 50000
#define NE 800000
#define HD 128
#define NG 32
#define GN_EPS 1e-5f
#define NSH 8

// radix CSR build params (800 blocks: rscatter needs TLP)
#define NBLK_R 800
#define CH_R   1000             // 800*1000 = NE
#define NBUCK  196              // dst>>8 buckets
#define NBB    (NBUCK * NBLK_R) // 156800
#define NCHS   ((NBB + 255) / 256)  // 613
#define DCAP   8192
#define PREP_BLKS 3125          // NN*16/256

typedef __bf16 v8bf __attribute__((ext_vector_type(8)));
typedef float f32x4 __attribute__((ext_vector_type(4)));
typedef unsigned int u32x4 __attribute__((ext_vector_type(4)));

// ---- ws layout (4-byte element offsets) ----
#define ROWPTR_OFF 0            // 50001 ints
#define BB_OFF     50016        // 156800 ints
#define CS_OFF     206816       // 1024 ints (613 used)
#define GSUMS_OFF  207840       // 8*4096 floats
#define GSQS_OFF   240608       // 8*4096 floats
#define GCNTS_OFF  273376       // 256 floats
#define MEAN_OFF   273632       // 4096 floats
#define RSTD_OFF   277728       // 4096 floats
#define SRCS_OFF   281824       // 800000 ushorts
#define PSRC_OFF   681824       // 800000 ushorts
#define PDLOW_OFF  1081824      // 800000 uchars
#define WPACK_OFF  1281824      // 32768 ushorts
#define XB_OFF     1298208      // 50000*128 ushorts (bf16 x, compact)
#define AGGB_OFF   4498208      // 50000*128 ushorts (bf16 agg, compact)
#define OBF_OFF    7698208      // 50000*128 ushorts (bf16 pre-norm out)
#define MEMSET_INTS (32768 + 32768 + 256)   // gsumS|gsqS|gcntS from GSUMS_OFF

__device__ __forceinline__ unsigned short f2bf(float f) {
  unsigned int u = __float_as_uint(f);
  u = (u + 0x7fffu + ((u >> 16) & 1u)) >> 16;   // RNE
  return (unsigned short)u;
}
__device__ __forceinline__ float bf_lo(unsigned int u) { return __uint_as_float(u << 16); }
__device__ __forceinline__ float bf_hi(unsigned int u) { return __uint_as_float(u & 0xffff0000u); }

// fused: [blocks 0..3124] zero stats + pack W + x f32->bf16 into compact xb
//        [blocks 3125..3924] radix histogram of dst>>8 (int4-vectorized)
__global__ __launch_bounds__(256) void prep_rhist_k(const float* __restrict__ x,
    const float* __restrict__ Wl, const float* __restrict__ Wr,
    unsigned short* __restrict__ xb, unsigned short* __restrict__ wp,
    int* __restrict__ zbase, const int* __restrict__ ei, int* __restrict__ bb) {
  __shared__ int h[NBUCK];
  int tid = threadIdx.x;
  if (blockIdx.x < PREP_BLKS) {
    int i = blockIdx.x * 256 + tid;
    if (i < MEMSET_INTS) zbase[i] = 0;
    if (i < 32768) {
      int e = i & 7, lane = (i >> 3) & 63, nt = (i >> 9) & 7, ks = i >> 12;
      int k = ks * 32 + (lane >> 4) * 8 + e;
      int c = nt * 16 + (lane & 15);
      float v = (k < HD) ? Wl[k * HD + c] : Wr[(k - HD) * HD + c];
      wp[i] = f2bf(v);
    }
    if (i < NN * 16) {
      int n = i >> 4, seg = i & 15;
      const float* src = x + (size_t)n * HD + seg * 8;
      float4 v0 = *(const float4*)(src);
      float4 v1 = *(const float4*)(src + 4);
      uint4 o;
      o.x = (unsigned)f2bf(v0.x) | ((unsigned)f2bf(v0.y) << 16);
      o.y = (unsigned)f2bf(v0.z) | ((unsigned)f2bf(v0.w) << 16);
      o.z = (unsigned)f2bf(v1.x) | ((unsigned)f2bf(v1.y) << 16);
      o.w = (unsigned)f2bf(v1.z) | ((unsigned)f2bf(v1.w) << 16);
      *(uint4*)(xb + (size_t)n * HD + seg * 8) = o;
    }
  } else {
    int b = blockIdx.x - PREP_BLKS;
    for (int i = tid; i < NBUCK; i += 256) h[i] = 0;
    __syncthreads();
    int base = b * CH_R;
    if (tid < CH_R / 4) {
      int4 d = *(const int4*)(ei + NE + base + tid * 4);
      atomicAdd(&h[d.x >> 8], 1);
      atomicAdd(&h[d.y >> 8], 1);
      atomicAdd(&h[d.z >> 8], 1);
      atomicAdd(&h[d.w >> 8], 1);
    }
    __syncthreads();
    for (int i = tid; i < NBUCK; i += 256) bb[i * NBLK_R + b] = h[i];
  }
}

// B1: chunk sums of bb (613 chunks of 256)
__global__ __launch_bounds__(256) void csum_k(const int* __restrict__ bb,
                                              int* __restrict__ cs) {
  __shared__ int red[4];
  int i = blockIdx.x * 256 + threadIdx.x;
  int v = (i < NBB) ? bb[i] : 0;
#pragma unroll
  for (int off = 32; off; off >>= 1) v += __shfl_down(v, off, 64);
  if ((threadIdx.x & 63) == 0) red[threadIdx.x >> 6] = v;
  __syncthreads();
  if (threadIdx.x == 0) cs[blockIdx.x] = red[0] + red[1] + red[2] + red[3];
}

// B2 (fused scan): 1024-thread blocks; each scans the 613 chunk sums in LDS
// (chunk prefix = sb[4*blk-1]) + in-block scan of its 1024 bb values.
__global__ __launch_bounds__(1024) void cfill_k(int* __restrict__ bb,
                                                const int* __restrict__ cs) {
  __shared__ int sb[1024];
  __shared__ int s[1024];
  int t = threadIdx.x;
  sb[t] = (t < NCHS) ? cs[t] : 0;
  int i = blockIdx.x * 1024 + t;
  int c = (i < NBB) ? bb[i] : 0;
  s[t] = c;
  __syncthreads();
  for (int off = 1; off < 1024; off <<= 1) {
    int u1 = (t >= off) ? sb[t - off] : 0;
    int u2 = (t >= off) ? s[t - off] : 0;
    __syncthreads();
    sb[t] += u1;
    s[t] += u2;
    __syncthreads();
  }
  int chunkpre = (blockIdx.x == 0) ? 0 : sb[blockIdx.x * 4 - 1];
  if (i < NBB) bb[i] = chunkpre + s[t] - c;
}

// C: scatter pass-1 (int4 ei reads, LDS cursors, no global atomics)
__global__ __launch_bounds__(256) void rscatter_k(const int* __restrict__ ei,
    const int* __restrict__ bb, unsigned short* __restrict__ psrc,
    unsigned char* __restrict__ pdlow) {
  __shared__ int cur[NBUCK];
  int tid = threadIdx.x, b = blockIdx.x;
  for (int i = tid; i < NBUCK; i += 256) cur[i] = bb[i * NBLK_R + b];
  __syncthreads();
  int base = b * CH_R;
  if (tid < CH_R / 4) {
    int4 s4 = *(const int4*)(ei + base + tid * 4);
    int4 d4 = *(const int4*)(ei + NE + base + tid * 4);
    int p;
    p = atomicAdd(&cur[d4.x >> 8], 1); psrc[p] = (unsigned short)s4.x; pdlow[p] = (unsigned char)(d4.x & 255);
    p = atomicAdd(&cur[d4.y >> 8], 1); psrc[p] = (unsigned short)s4.y; pdlow[p] = (unsigned char)(d4.y & 255);
    p = atomicAdd(&cur[d4.z >> 8], 1); psrc[p] = (unsigned short)s4.z; pdlow[p] = (unsigned char)(d4.z & 255);
    p = atomicAdd(&cur[d4.w >> 8], 1); psrc[p] = (unsigned short)s4.w; pdlow[p] = (unsigned char)(d4.w & 255);
  }
}

// D: pass-2 inside one bucket: LDS hist256 + scan + place; coalesced srcs out
__global__ __launch_bounds__(256) void rfinal_k(const int* __restrict__ bb,
    const unsigned short* __restrict__ psrc, const unsigned char* __restrict__ pdlow,
    unsigned short* __restrict__ srcs, int* __restrict__ rowptr) {
  __shared__ unsigned short ssrc[DCAP];
  __shared__ unsigned short sout[DCAP];
  __shared__ unsigned char sdl[DCAP];
  __shared__ int h2[256], scn[256], cur2[256];
  int tid = threadIdx.x, k = blockIdx.x;
  int segB = bb[k * NBLK_R];
  int segE = (k == NBUCK - 1) ? NE : bb[(k + 1) * NBLK_R];
  int cnt = segE - segB;
  for (int j = tid; j < cnt; j += 256) {
    ssrc[j] = psrc[segB + j];
    sdl[j] = pdlow[segB + j];
  }
  h2[tid] = 0;
  __syncthreads();
  for (int j = tid; j < cnt; j += 256) atomicAdd(&h2[sdl[j]], 1);
  __syncthreads();
  scn[tid] = h2[tid];
  __syncthreads();
#pragma unroll
  for (int off = 1; off < 256; off <<= 1) {
    int u = (tid >= off) ? scn[tid - off] : 0;
    __syncthreads();
    scn[tid] += u;
    __syncthreads();
  }
  int excl = scn[tid] - h2[tid];
  cur2[tid] = excl;
  int dst = k * 256 + tid;
  if (dst < NN) rowptr[dst] = segB + excl;
  if (dst == NN - 1) rowptr[NN] = NE;
  __syncthreads();
  for (int j = tid; j < cnt; j += 256) {
    int p = atomicAdd(&cur2[sdl[j]], 1);
    sout[p] = ssrc[j];
  }
  __syncthreads();
  for (int j = tid; j < cnt; j += 256) srcs[segB + j] = sout[j];
}

// monolithic gather (R16 windowing refuted: broke MLP). 4-edge unroll for MLP;
// agg written NON-TEMPORAL (clang ext_vector type) -> no L2 pollution of the
// 12.8MB x working set.
__global__ __launch_bounds__(256) void gather_k(const int* __restrict__ rowptr,
    const unsigned short* __restrict__ srcs, const unsigned short* __restrict__ xb,
    unsigned short* __restrict__ aggb) {
  int t = blockIdx.x * 256 + threadIdx.x;
  int n = t >> 4, q = t & 15;
  if (n >= NN) return;
  int b = rowptr[n], e = rowptr[n + 1];
  float a0=0,a1=0,a2=0,a3=0,a4=0,a5=0,a6=0,a7=0;
  int i = b;
  for (; i + 3 < e; i += 4) {
    int s0 = srcs[i], s1 = srcs[i + 1], s2 = srcs[i + 2], s3 = srcs[i + 3];
    uint4 v0 = *(const uint4*)(xb + (size_t)s0 * HD + q * 8);
    uint4 v1 = *(const uint4*)(xb + (size_t)s1 * HD + q * 8);
    uint4 v2 = *(const uint4*)(xb + (size_t)s2 * HD + q * 8);
    uint4 v3 = *(const uint4*)(xb + (size_t)s3 * HD + q * 8);
    a0 += (bf_lo(v0.x) + bf_lo(v1.x)) + (bf_lo(v2.x) + bf_lo(v3.x));
    a1 += (bf_hi(v0.x) + bf_hi(v1.x)) + (bf_hi(v2.x) + bf_hi(v3.x));
    a2 += (bf_lo(v0.y) + bf_lo(v1.y)) + (bf_lo(v2.y) + bf_lo(v3.y));
    a3 += (bf_hi(v0.y) + bf_hi(v1.y)) + (bf_hi(v2.y) + bf_hi(v3.y));
    a4 += (bf_lo(v0.z) + bf_lo(v1.z)) + (bf_lo(v2.z) + bf_lo(v3.z));
    a5 += (bf_hi(v0.z) + bf_hi(v1.z)) + (bf_hi(v2.z) + bf_hi(v3.z));
    a6 += (bf_lo(v0.w) + bf_lo(v1.w)) + (bf_lo(v2.w) + bf_lo(v3.w));
    a7 += (bf_hi(v0.w) + bf_hi(v1.w)) + (bf_hi(v2.w) + bf_hi(v3.w));
  }
  for (; i < e; ++i) {
    int s0 = srcs[i];
    uint4 v0 = *(const uint4*)(xb + (size_t)s0 * HD + q * 8);
    a0 += bf_lo(v0.x); a1 += bf_hi(v0.x);
    a2 += bf_lo(v0.y); a3 += bf_hi(v0.y);
    a4 += bf_lo(v0.z); a5 += bf_hi(v0.z);
    a6 += bf_lo(v0.w); a7 += bf_hi(v0.w);
  }
  float inv = 1.0f / fmaxf((float)(e - b), 1.0f);
  u32x4 o;
  o.x = (unsigned)f2bf(a0 * inv) | ((unsigned)f2bf(a1 * inv) << 16);
  o.y = (unsigned)f2bf(a2 * inv) | ((unsigned)f2bf(a3 * inv) << 16);
  o.z = (unsigned)f2bf(a4 * inv) | ((unsigned)f2bf(a5 * inv) << 16);
  o.w = (unsigned)f2bf(a6 * inv) | ((unsigned)f2bf(a7 * inv) << 16);
  __builtin_nontemporal_store(o, (u32x4*)(aggb + (size_t)n * HD + q * 8));
}

// MFMA GEMM + fused GraphNorm stats (per-XCD-shard partials); bf16 obf out.
// A-operand: ks<4 from aggb, ks>=4 from xb (both compact [NN][128]).
__global__ __launch_bounds__(256) void gemm_k(const unsigned short* __restrict__ aggb,
    const unsigned short* __restrict__ xb,
    const unsigned short* __restrict__ wp, const float* __restrict__ bl,
    const int* __restrict__ batch, unsigned short* __restrict__ obf,
    float* __restrict__ gsumS, float* __restrict__ gsqS,
    float* __restrict__ gcntS) {
  __shared__ float lsum[16][136];
  __shared__ float lsq[16][136];
  __shared__ unsigned char ridx[64];
  __shared__ int sg0, snrun;
  int tid = threadIdx.x;
  int base0 = blockIdx.x * 64;
  int nvalid = min(64, NN - base0);
  if (tid == 0) {
    int g0 = batch[base0];
    sg0 = g0;
    snrun = batch[base0 + nvalid - 1] - g0 + 1;
  }
  __syncthreads();
  if (tid < 64)
    ridx[tid] = (tid < nvalid) ? (unsigned char)(batch[base0 + tid] - sg0)
                               : (unsigned char)0;
  __syncthreads();

  int shard = blockIdx.x & 7;
  float* gs = gsumS + shard * (NG * HD);
  float* gq = gsqS + shard * (NG * HD);
  float* gc = gcntS + shard * NG;

  int wave = tid >> 6;
  int lane = tid & 63;
  int base = base0 + wave * 16;
  int row = lane & 15, kg = lane >> 4;
  int node = base + row;
  if (node > NN - 1) node = NN - 1;
  const unsigned short* arow = aggb + (size_t)node * HD + kg * 8;
  const unsigned short* xrow = xb + (size_t)node * HD + kg * 8;
  f32x4 acc[8] = {};
#pragma unroll
  for (int ks = 0; ks < 8; ++ks) {
    const unsigned short* aptr = (ks < 4) ? (arow + ks * 32) : (xrow + (ks - 4) * 32);
    v8bf a = __builtin_bit_cast(v8bf, *(const uint4*)aptr);
    const unsigned short* wrow = wp + ks * 4096 + lane * 8;
#pragma unroll
    for (int nt = 0; nt < 8; ++nt) {
      v8bf b = __builtin_bit_cast(v8bf, *(const uint4*)(wrow + nt * 512));
      acc[nt] = __builtin_amdgcn_mfma_f32_16x16x32_bf16(a, b, acc[nt], 0, 0, 0);
    }
  }
  int c0 = lane & 15;
  float bv[8];
#pragma unroll
  for (int nt = 0; nt < 8; ++nt) bv[nt] = bl[nt * 16 + c0];

  if (snrun == 1) {
    float ps0[8] = {}, pq0[8] = {};
#pragma unroll
    for (int j = 0; j < 4; ++j) {
      int n = base0 + wave * 16 + kg * 4 + j;
      if (n >= NN) break;
      unsigned short* orow = obf + (size_t)n * HD;
#pragma unroll
      for (int nt = 0; nt < 8; ++nt) {
        float v = acc[nt][j] + bv[nt];
        orow[nt * 16 + c0] = f2bf(v);
        ps0[nt] += v;
        pq0[nt] += v * v;
      }
    }
    int r = wave * 4 + kg;
#pragma unroll
    for (int nt = 0; nt < 8; ++nt) {
      lsum[r][nt * 16 + c0] = ps0[nt];
      lsq[r][nt * 16 + c0] = pq0[nt];
    }
    __syncthreads();
    if (tid < HD) {
      float s = 0.0f, q = 0.0f;
#pragma unroll
      for (int r2 = 0; r2 < 16; ++r2) { s += lsum[r2][tid]; q += lsq[r2][tid]; }
      atomicAdd(gs + sg0 * HD + tid, s);
      atomicAdd(gq + sg0 * HD + tid, q);
    }
    if (tid == 0) atomicAdd(gc + sg0, (float)nvalid);
  } else if (snrun == 2) {
    float ps0[8] = {}, pq0[8] = {}, ps1[8] = {}, pq1[8] = {};
#pragma unroll
    for (int j = 0; j < 4; ++j) {
      int rb = wave * 16 + kg * 4 + j;
      int n = base0 + rb;
      if (n >= NN) break;
      unsigned short* orow = obf + (size_t)n * HD;
      bool b1 = (ridx[rb] != 0);
#pragma unroll
      for (int nt = 0; nt < 8; ++nt) {
        float v = acc[nt][j] + bv[nt];
        orow[nt * 16 + c0] = f2bf(v);
        if (b1) { ps1[nt] += v; pq1[nt] += v * v; }
        else    { ps0[nt] += v; pq0[nt] += v * v; }
      }
    }
    int r = wave * 4 + kg;
#pragma unroll
    for (int nt = 0; nt < 8; ++nt) {
      lsum[r][nt * 16 + c0] = ps0[nt];
      lsq[r][nt * 16 + c0] = pq0[nt];
    }
    __syncthreads();
    if (tid < HD) {
      float s = 0.0f, q = 0.0f;
#pragma unroll
      for (int r2 = 0; r2 < 16; ++r2) { s += lsum[r2][tid]; q += lsq[r2][tid]; }
      atomicAdd(gs + sg0 * HD + tid, s);
      atomicAdd(gq + sg0 * HD + tid, q);
    }
    __syncthreads();
#pragma unroll
    for (int nt = 0; nt < 8; ++nt) {
      lsum[r][nt * 16 + c0] = ps1[nt];
      lsq[r][nt * 16 + c0] = pq1[nt];
    }
    __syncthreads();
    if (tid < HD) {
      float s = 0.0f, q = 0.0f;
#pragma unroll
      for (int r2 = 0; r2 < 16; ++r2) { s += lsum[r2][tid]; q += lsq[r2][tid]; }
      atomicAdd(gs + (sg0 + 1) * HD + tid, s);
      atomicAdd(gq + (sg0 + 1) * HD + tid, q);
    }
    if (tid == 0) {
      int n0 = 0;
      for (int r2 = 0; r2 < nvalid; ++r2) n0 += (ridx[r2] == 0);
      atomicAdd(gc + sg0, (float)n0);
      atomicAdd(gc + sg0 + 1, (float)(nvalid - n0));
    }
  } else {
#pragma unroll
    for (int j = 0; j < 4; ++j) {
      int rb = wave * 16 + kg * 4 + j;
      int n = base0 + rb;
      if (n >= NN) break;
      unsigned short* orow = obf + (size_t)n * HD;
      int g = sg0 + ridx[rb];
#pragma unroll
      for (int nt = 0; nt < 8; ++nt) {
        float v = acc[nt][j] + bv[nt];
        orow[nt * 16 + c0] = f2bf(v);
        atomicAdd(gs + g * HD + nt * 16 + c0, v);
        atomicAdd(gq + g * HD + nt * 16 + c0, v * v);
      }
    }
    if (tid < nvalid) atomicAdd(gc + batch[base0 + tid], 1.0f);
  }
}

// reduce 8 shard partials -> mean, rstd
__global__ __launch_bounds__(256) void finalize_k(const float* __restrict__ gsumS,
    const float* __restrict__ gsqS, const float* __restrict__ gcntS,
    const float* __restrict__ alpha, float* __restrict__ mean,
    float* __restrict__ rstd) {
  int i = blockIdx.x * 256 + threadIdx.x;
  if (i >= NG * HD) return;
  int g = i >> 7, d = i & 127;
  float s = 0.0f, q = 0.0f, cnt = 0.0f;
#pragma unroll
  for (int sh = 0; sh < NSH; ++sh) {
    s += gsumS[sh * (NG * HD) + i];
    q += gsqS[sh * (NG * HD) + i];
    cnt += gcntS[sh * NG + g];
  }
  cnt = fmaxf(cnt, 1.0f);
  float mu = s / cnt;
  float a = alpha[d];
  float var = q / cnt - mu * mu * (2.0f * a - a * a);
  mean[i] = mu;
  rstd[i] = rsqrtf(fmaxf(var, 0.0f) + GN_EPS);
}

// norm + GELU + residual: reads bf16 obf + f32 x, writes f32 d_out
__global__ __launch_bounds__(256) void final_k(const unsigned short* __restrict__ obf,
    float* __restrict__ out, const float* __restrict__ x,
    const int* __restrict__ batch, const float* __restrict__ mean,
    const float* __restrict__ rstd, const float* __restrict__ alpha,
    const float* __restrict__ gw, const float* __restrict__ gb) {
  size_t i = ((size_t)blockIdx.x * 256 + threadIdx.x) * 4;
  if (i >= (size_t)NN * HD) return;
  int n = (int)(i >> 7);
  int d = (int)(i & 127);
  int g = batch[n];
  uint2 ov = *(const uint2*)(obf + i);
  float4 xv = *(const float4*)(x + i);
  float4 al = *(const float4*)(alpha + d);
  float4 w  = *(const float4*)(gw + d);
  float4 b  = *(const float4*)(gb + d);
  float4 mn = *(const float4*)(mean + (size_t)g * HD + d);
  float4 rs = *(const float4*)(rstd + (size_t)g * HD + d);
  float vv[4] = {bf_lo(ov.x), bf_hi(ov.x), bf_lo(ov.y), bf_hi(ov.y)};
  float xx[4] = {xv.x, xv.y, xv.z, xv.w};
  float aa[4] = {al.x, al.y, al.z, al.w};
  float ww[4] = {w.x, w.y, w.z, w.w};
  float bb2[4] = {b.x, b.y, b.z, b.w};
  float mm[4] = {mn.x, mn.y, mn.z, mn.w};
  float rr[4] = {rs.x, rs.y, rs.z, rs.w};
  float r[4];
#pragma unroll
  for (int c = 0; c < 4; ++c) {
    float sub = vv[c] - aa[c] * mm[c];
    float nm  = ww[c] * sub * rr[c] + bb2[c];
    float ge  = 0.5f * nm * (1.0f + erff(nm * 0.70710678118654752f));
    r[c] = ge + xx[c];
  }
  float4 res = {r[0], r[1], r[2], r[3]};
  *(float4*)(out + i) = res;
}

extern "C" void kernel_launch(void* const* d_in, const int* in_sizes, int n_in,
                              void* d_out, int out_size, void* d_ws, size_t ws_size,
                              hipStream_t stream) {
  const float* x     = (const float*)d_in[0];
  const int*   ei    = (const int*)d_in[1];
  const int*   batch = (const int*)d_in[2];
  const float* Wl    = (const float*)d_in[3];
  const float* bl    = (const float*)d_in[4];
  const float* Wr    = (const float*)d_in[5];
  const float* gw    = (const float*)d_in[6];
  const float* gb    = (const float*)d_in[7];
  const float* alpha = (const float*)d_in[8];

  float* out = (float*)d_out;
  int*   wsi = (int*)d_ws;
  float* wsf = (float*)d_ws;
  int* rowptr = wsi + ROWPTR_OFF;
  int* bb     = wsi + BB_OFF;
  int* cs     = wsi + CS_OFF;
  float* gsumS = wsf + GSUMS_OFF;
  float* gsqS  = wsf + GSQS_OFF;
  float* gcntS = wsf + GCNTS_OFF;
  float* mean  = wsf + MEAN_OFF;
  float* rstd  = wsf + RSTD_OFF;
  unsigned short* srcs  = (unsigned short*)(wsi + SRCS_OFF);
  unsigned short* psrc  = (unsigned short*)(wsi + PSRC_OFF);
  unsigned char*  pdlow = (unsigned char*)(wsi + PDLOW_OFF);
  unsigned short* wpack = (unsigned short*)(wsi + WPACK_OFF);
  unsigned short* xb    = (unsigned short*)(wsi + XB_OFF);
  unsigned short* aggb  = (unsigned short*)(wsi + AGGB_OFF);
  unsigned short* obf   = (unsigned short*)(wsi + OBF_OFF);

  prep_rhist_k<<<PREP_BLKS + NBLK_R, 256, 0, stream>>>(
      x, Wl, Wr, xb, wpack, (int*)(wsf + GSUMS_OFF), ei, bb);

  csum_k<<<NCHS, 256, 0, stream>>>(bb, cs);
  cfill_k<<<(NBB + 1023) / 1024, 1024, 0, stream>>>(bb, cs);
  rscatter_k<<<NBLK_R, 256, 0, stream>>>(ei, bb, psrc, pdlow);
  rfinal_k<<<NBUCK, 256, 0, stream>>>(bb, psrc, pdlow, srcs, rowptr);

  gather_k<<<(NN * 16 + 255) / 256, 256, 0, stream>>>(rowptr, srcs, xb, aggb);

  gemm_k<<<(NN + 63) / 64, 256, 0, stream>>>(aggb, xb, wpack, bl, batch, obf,
                                             gsumS, gsqS, gcntS);

  finalize_k<<<16, 256, 0, stream>>>(gsumS, gsqS, gcntS, alpha, mean, rstd);

  final_k<<<(NN * HD / 4 + 255) / 256, 256, 0, stream>>>(
      obf, out, x, batch, mean, rstd, alpha, gw, gb);
}

// Round 21
// 97.192 us; speedup vs baseline: 1.7443x; 1.0024x over previous
//
#include <hip/hip_runtime.h>
#include <math.h>

#define NN 50000
#define NE 800000
#define HD 128
#define NG 32
#define GN_EPS 1e-5f
#define NSH 8

// radix CSR build params (800 blocks: rscatter needs TLP)
#define NBLK_R 800
#define CH_R   1000             // 800*1000 = NE
#define NBUCK  196              // dst>>8 buckets
#define NBB    (NBUCK * NBLK_R) // 156800
#define NCHS   ((NBB + 255) / 256)  // 613
#define DCAP   8192
#define PREP_BLKS 3125          // NN*16/256

typedef __bf16 v8bf __attribute__((ext_vector_type(8)));
typedef float f32x4 __attribute__((ext_vector_type(4)));
typedef unsigned int u32x4 __attribute__((ext_vector_type(4)));

// ---- ws layout (4-byte element offsets) ----
#define ROWPTR_OFF 0            // 50001 ints
#define BB_OFF     50016        // 156800 ints
#define CS_OFF     206816       // 1024 ints (613 used)
#define GSUMS_OFF  207840       // 8*4096 floats
#define GSQS_OFF   240608       // 8*4096 floats
#define GCNTS_OFF  273376       // 256 floats
#define MEAN_OFF   273632       // 4096 floats
#define RSTD_OFF   277728       // 4096 floats
#define SRCS_OFF   281824       // 800000 ushorts
#define PSRC_OFF   681824       // 800000 ushorts
#define PDLOW_OFF  1081824      // 800000 uchars
#define WPACK_OFF  1281824      // 32768 ushorts
#define XB_OFF     1298208      // 50000*128 ushorts (bf16 x, compact)
#define AGGB_OFF   4498208      // 50000*128 ushorts (bf16 agg, compact)
#define OBF_OFF    7698208      // 50000*128 ushorts (bf16 pre-norm out)
#define MEMSET_INTS (32768 + 32768 + 256)   // gsumS|gsqS|gcntS from GSUMS_OFF

__device__ __forceinline__ unsigned short f2bf(float f) {
  unsigned int u = __float_as_uint(f);
  u = (u + 0x7fffu + ((u >> 16) & 1u)) >> 16;   // RNE
  return (unsigned short)u;
}
__device__ __forceinline__ float bf_lo(unsigned int u) { return __uint_as_float(u << 16); }
__device__ __forceinline__ float bf_hi(unsigned int u) { return __uint_as_float(u & 0xffff0000u); }

// fused: [blocks 0..3124] zero stats + pack W + x f32->bf16 into compact xb
//        [blocks 3125..3924] radix histogram of dst>>8 (int4-vectorized)
__global__ __launch_bounds__(256) void prep_rhist_k(const float* __restrict__ x,
    const float* __restrict__ Wl, const float* __restrict__ Wr,
    unsigned short* __restrict__ xb, unsigned short* __restrict__ wp,
    int* __restrict__ zbase, const int* __restrict__ ei, int* __restrict__ bb) {
  __shared__ int h[NBUCK];
  int tid = threadIdx.x;
  if (blockIdx.x < PREP_BLKS) {
    int i = blockIdx.x * 256 + tid;
    if (i < MEMSET_INTS) zbase[i] = 0;
    if (i < 32768) {
      int e = i & 7, lane = (i >> 3) & 63, nt = (i >> 9) & 7, ks = i >> 12;
      int k = ks * 32 + (lane >> 4) * 8 + e;
      int c = nt * 16 + (lane & 15);
      float v = (k < HD) ? Wl[k * HD + c] : Wr[(k - HD) * HD + c];
      wp[i] = f2bf(v);
    }
    if (i < NN * 16) {
      int n = i >> 4, seg = i & 15;
      const float* src = x + (size_t)n * HD + seg * 8;
      float4 v0 = *(const float4*)(src);
      float4 v1 = *(const float4*)(src + 4);
      uint4 o;
      o.x = (unsigned)f2bf(v0.x) | ((unsigned)f2bf(v0.y) << 16);
      o.y = (unsigned)f2bf(v0.z) | ((unsigned)f2bf(v0.w) << 16);
      o.z = (unsigned)f2bf(v1.x) | ((unsigned)f2bf(v1.y) << 16);
      o.w = (unsigned)f2bf(v1.z) | ((unsigned)f2bf(v1.w) << 16);
      *(uint4*)(xb + (size_t)n * HD + seg * 8) = o;
    }
  } else {
    int b = blockIdx.x - PREP_BLKS;
    for (int i = tid; i < NBUCK; i += 256) h[i] = 0;
    __syncthreads();
    int base = b * CH_R;
    if (tid < CH_R / 4) {
      int4 d = *(const int4*)(ei + NE + base + tid * 4);
      atomicAdd(&h[d.x >> 8], 1);
      atomicAdd(&h[d.y >> 8], 1);
      atomicAdd(&h[d.z >> 8], 1);
      atomicAdd(&h[d.w >> 8], 1);
    }
    __syncthreads();
    for (int i = tid; i < NBUCK; i += 256) bb[i * NBLK_R + b] = h[i];
  }
}

// B1: chunk sums of bb (613 chunks of 256)
__global__ __launch_bounds__(256) void csum_k(const int* __restrict__ bb,
                                              int* __restrict__ cs) {
  __shared__ int red[4];
  int i = blockIdx.x * 256 + threadIdx.x;
  int v = (i < NBB) ? bb[i] : 0;
#pragma unroll
  for (int off = 32; off; off >>= 1) v += __shfl_down(v, off, 64);
  if ((threadIdx.x & 63) == 0) red[threadIdx.x >> 6] = v;
  __syncthreads();
  if (threadIdx.x == 0) cs[blockIdx.x] = red[0] + red[1] + red[2] + red[3];
}

// B2 (fused scan): 1024-thread blocks; each scans the 613 chunk sums in LDS
// (chunk prefix = sb[4*blk-1]) + in-block scan of its 1024 bb values.
__global__ __launch_bounds__(1024) void cfill_k(int* __restrict__ bb,
                                                const int* __restrict__ cs) {
  __shared__ int sb[1024];
  __shared__ int s[1024];
  int t = threadIdx.x;
  sb[t] = (t < NCHS) ? cs[t] : 0;
  int i = blockIdx.x * 1024 + t;
  int c = (i < NBB) ? bb[i] : 0;
  s[t] = c;
  __syncthreads();
  for (int off = 1; off < 1024; off <<= 1) {
    int u1 = (t >= off) ? sb[t - off] : 0;
    int u2 = (t >= off) ? s[t - off] : 0;
    __syncthreads();
    sb[t] += u1;
    s[t] += u2;
    __syncthreads();
  }
  int chunkpre = (blockIdx.x == 0) ? 0 : sb[blockIdx.x * 4 - 1];
  if (i < NBB) bb[i] = chunkpre + s[t] - c;
}

// C: scatter pass-1 (int4 ei reads, LDS cursors, no global atomics)
__global__ __launch_bounds__(256) void rscatter_k(const int* __restrict__ ei,
    const int* __restrict__ bb, unsigned short* __restrict__ psrc,
    unsigned char* __restrict__ pdlow) {
  __shared__ int cur[NBUCK];
  int tid = threadIdx.x, b = blockIdx.x;
  for (int i = tid; i < NBUCK; i += 256) cur[i] = bb[i * NBLK_R + b];
  __syncthreads();
  int base = b * CH_R;
  if (tid < CH_R / 4) {
    int4 s4 = *(const int4*)(ei + base + tid * 4);
    int4 d4 = *(const int4*)(ei + NE + base + tid * 4);
    int p;
    p = atomicAdd(&cur[d4.x >> 8], 1); psrc[p] = (unsigned short)s4.x; pdlow[p] = (unsigned char)(d4.x & 255);
    p = atomicAdd(&cur[d4.y >> 8], 1); psrc[p] = (unsigned short)s4.y; pdlow[p] = (unsigned char)(d4.y & 255);
    p = atomicAdd(&cur[d4.z >> 8], 1); psrc[p] = (unsigned short)s4.z; pdlow[p] = (unsigned char)(d4.z & 255);
    p = atomicAdd(&cur[d4.w >> 8], 1); psrc[p] = (unsigned short)s4.w; pdlow[p] = (unsigned char)(d4.w & 255);
  }
}

// D: pass-2 inside one bucket: LDS hist256 + scan + place; coalesced srcs out
__global__ __launch_bounds__(256) void rfinal_k(const int* __restrict__ bb,
    const unsigned short* __restrict__ psrc, const unsigned char* __restrict__ pdlow,
    unsigned short* __restrict__ srcs, int* __restrict__ rowptr) {
  __shared__ unsigned short ssrc[DCAP];
  __shared__ unsigned short sout[DCAP];
  __shared__ unsigned char sdl[DCAP];
  __shared__ int h2[256], scn[256], cur2[256];
  int tid = threadIdx.x, k = blockIdx.x;
  int segB = bb[k * NBLK_R];
  int segE = (k == NBUCK - 1) ? NE : bb[(k + 1) * NBLK_R];
  int cnt = segE - segB;
  for (int j = tid; j < cnt; j += 256) {
    ssrc[j] = psrc[segB + j];
    sdl[j] = pdlow[segB + j];
  }
  h2[tid] = 0;
  __syncthreads();
  for (int j = tid; j < cnt; j += 256) atomicAdd(&h2[sdl[j]], 1);
  __syncthreads();
  scn[tid] = h2[tid];
  __syncthreads();
#pragma unroll
  for (int off = 1; off < 256; off <<= 1) {
    int u = (tid >= off) ? scn[tid - off] : 0;
    __syncthreads();
    scn[tid] += u;
    __syncthreads();
  }
  int excl = scn[tid] - h2[tid];
  cur2[tid] = excl;
  int dst = k * 256 + tid;
  if (dst < NN) rowptr[dst] = segB + excl;
  if (dst == NN - 1) rowptr[NN] = NE;
  __syncthreads();
  for (int j = tid; j < cnt; j += 256) {
    int p = atomicAdd(&cur2[sdl[j]], 1);
    sout[p] = ssrc[j];
  }
  __syncthreads();
  for (int j = tid; j < cnt; j += 256) srcs[segB + j] = sout[j];
}

// monolithic gather; 4-edge unroll for MLP; NT agg stores (no L2 pollution)
__global__ __launch_bounds__(256) void gather_k(const int* __restrict__ rowptr,
    const unsigned short* __restrict__ srcs, const unsigned short* __restrict__ xb,
    unsigned short* __restrict__ aggb) {
  int t = blockIdx.x * 256 + threadIdx.x;
  int n = t >> 4, q = t & 15;
  if (n >= NN) return;
  int b = rowptr[n], e = rowptr[n + 1];
  float a0=0,a1=0,a2=0,a3=0,a4=0,a5=0,a6=0,a7=0;
  int i = b;
  for (; i + 3 < e; i += 4) {
    int s0 = srcs[i], s1 = srcs[i + 1], s2 = srcs[i + 2], s3 = srcs[i + 3];
    uint4 v0 = *(const uint4*)(xb + (size_t)s0 * HD + q * 8);
    uint4 v1 = *(const uint4*)(xb + (size_t)s1 * HD + q * 8);
    uint4 v2 = *(const uint4*)(xb + (size_t)s2 * HD + q * 8);
    uint4 v3 = *(const uint4*)(xb + (size_t)s3 * HD + q * 8);
    a0 += (bf_lo(v0.x) + bf_lo(v1.x)) + (bf_lo(v2.x) + bf_lo(v3.x));
    a1 += (bf_hi(v0.x) + bf_hi(v1.x)) + (bf_hi(v2.x) + bf_hi(v3.x));
    a2 += (bf_lo(v0.y) + bf_lo(v1.y)) + (bf_lo(v2.y) + bf_lo(v3.y));
    a3 += (bf_hi(v0.y) + bf_hi(v1.y)) + (bf_hi(v2.y) + bf_hi(v3.y));
    a4 += (bf_lo(v0.z) + bf_lo(v1.z)) + (bf_lo(v2.z) + bf_lo(v3.z));
    a5 += (bf_hi(v0.z) + bf_hi(v1.z)) + (bf_hi(v2.z) + bf_hi(v3.z));
    a6 += (bf_lo(v0.w) + bf_lo(v1.w)) + (bf_lo(v2.w) + bf_lo(v3.w));
    a7 += (bf_hi(v0.w) + bf_hi(v1.w)) + (bf_hi(v2.w) + bf_hi(v3.w));
  }
  for (; i < e; ++i) {
    int s0 = srcs[i];
    uint4 v0 = *(const uint4*)(xb + (size_t)s0 * HD + q * 8);
    a0 += bf_lo(v0.x); a1 += bf_hi(v0.x);
    a2 += bf_lo(v0.y); a3 += bf_hi(v0.y);
    a4 += bf_lo(v0.z); a5 += bf_hi(v0.z);
    a6 += bf_lo(v0.w); a7 += bf_hi(v0.w);
  }
  float inv = 1.0f / fmaxf((float)(e - b), 1.0f);
  u32x4 o;
  o.x = (unsigned)f2bf(a0 * inv) | ((unsigned)f2bf(a1 * inv) << 16);
  o.y = (unsigned)f2bf(a2 * inv) | ((unsigned)f2bf(a3 * inv) << 16);
  o.z = (unsigned)f2bf(a4 * inv) | ((unsigned)f2bf(a5 * inv) << 16);
  o.w = (unsigned)f2bf(a6 * inv) | ((unsigned)f2bf(a7 * inv) << 16);
  __builtin_nontemporal_store(o, (u32x4*)(aggb + (size_t)n * HD + q * 8));
}

// MFMA GEMM + fused GraphNorm stats (per-XCD-shard partials); bf16 obf out.
__global__ __launch_bounds__(256) void gemm_k(const unsigned short* __restrict__ aggb,
    const unsigned short* __restrict__ xb,
    const unsigned short* __restrict__ wp, const float* __restrict__ bl,
    const int* __restrict__ batch, unsigned short* __restrict__ obf,
    float* __restrict__ gsumS, float* __restrict__ gsqS,
    float* __restrict__ gcntS) {
  __shared__ float lsum[16][136];
  __shared__ float lsq[16][136];
  __shared__ unsigned char ridx[64];
  __shared__ int sg0, snrun;
  int tid = threadIdx.x;
  int base0 = blockIdx.x * 64;
  int nvalid = min(64, NN - base0);
  if (tid == 0) {
    int g0 = batch[base0];
    sg0 = g0;
    snrun = batch[base0 + nvalid - 1] - g0 + 1;
  }
  __syncthreads();
  if (tid < 64)
    ridx[tid] = (tid < nvalid) ? (unsigned char)(batch[base0 + tid] - sg0)
                               : (unsigned char)0;
  __syncthreads();

  int shard = blockIdx.x & 7;
  float* gs = gsumS + shard * (NG * HD);
  float* gq = gsqS + shard * (NG * HD);
  float* gc = gcntS + shard * NG;

  int wave = tid >> 6;
  int lane = tid & 63;
  int base = base0 + wave * 16;
  int row = lane & 15, kg = lane >> 4;
  int node = base + row;
  if (node > NN - 1) node = NN - 1;
  const unsigned short* arow = aggb + (size_t)node * HD + kg * 8;
  const unsigned short* xrow = xb + (size_t)node * HD + kg * 8;
  f32x4 acc[8] = {};
#pragma unroll
  for (int ks = 0; ks < 8; ++ks) {
    const unsigned short* aptr = (ks < 4) ? (arow + ks * 32) : (xrow + (ks - 4) * 32);
    v8bf a = __builtin_bit_cast(v8bf, *(const uint4*)aptr);
    const unsigned short* wrow = wp + ks * 4096 + lane * 8;
#pragma unroll
    for (int nt = 0; nt < 8; ++nt) {
      v8bf b = __builtin_bit_cast(v8bf, *(const uint4*)(wrow + nt * 512));
      acc[nt] = __builtin_amdgcn_mfma_f32_16x16x32_bf16(a, b, acc[nt], 0, 0, 0);
    }
  }
  int c0 = lane & 15;
  float bv[8];
#pragma unroll
  for (int nt = 0; nt < 8; ++nt) bv[nt] = bl[nt * 16 + c0];

  if (snrun == 1) {
    float ps0[8] = {}, pq0[8] = {};
#pragma unroll
    for (int j = 0; j < 4; ++j) {
      int n = base0 + wave * 16 + kg * 4 + j;
      if (n >= NN) break;
      unsigned short* orow = obf + (size_t)n * HD;
#pragma unroll
      for (int nt = 0; nt < 8; ++nt) {
        float v = acc[nt][j] + bv[nt];
        orow[nt * 16 + c0] = f2bf(v);
        ps0[nt] += v;
        pq0[nt] += v * v;
      }
    }
    int r = wave * 4 + kg;
#pragma unroll
    for (int nt = 0; nt < 8; ++nt) {
      lsum[r][nt * 16 + c0] = ps0[nt];
      lsq[r][nt * 16 + c0] = pq0[nt];
    }
    __syncthreads();
    if (tid < HD) {
      float s = 0.0f, q = 0.0f;
#pragma unroll
      for (int r2 = 0; r2 < 16; ++r2) { s += lsum[r2][tid]; q += lsq[r2][tid]; }
      atomicAdd(gs + sg0 * HD + tid, s);
      atomicAdd(gq + sg0 * HD + tid, q);
    }
    if (tid == 0) atomicAdd(gc + sg0, (float)nvalid);
  } else if (snrun == 2) {
    float ps0[8] = {}, pq0[8] = {}, ps1[8] = {}, pq1[8] = {};
#pragma unroll
    for (int j = 0; j < 4; ++j) {
      int rb = wave * 16 + kg * 4 + j;
      int n = base0 + rb;
      if (n >= NN) break;
      unsigned short* orow = obf + (size_t)n * HD;
      bool b1 = (ridx[rb] != 0);
#pragma unroll
      for (int nt = 0; nt < 8; ++nt) {
        float v = acc[nt][j] + bv[nt];
        orow[nt * 16 + c0] = f2bf(v);
        if (b1) { ps1[nt] += v; pq1[nt] += v * v; }
        else    { ps0[nt] += v; pq0[nt] += v * v; }
      }
    }
    int r = wave * 4 + kg;
#pragma unroll
    for (int nt = 0; nt < 8; ++nt) {
      lsum[r][nt * 16 + c0] = ps0[nt];
      lsq[r][nt * 16 + c0] = pq0[nt];
    }
    __syncthreads();
    if (tid < HD) {
      float s = 0.0f, q = 0.0f;
#pragma unroll
      for (int r2 = 0; r2 < 16; ++r2) { s += lsum[r2][tid]; q += lsq[r2][tid]; }
      atomicAdd(gs + sg0 * HD + tid, s);
      atomicAdd(gq + sg0 * HD + tid, q);
    }
    __syncthreads();
#pragma unroll
    for (int nt = 0; nt < 8; ++nt) {
      lsum[r][nt * 16 + c0] = ps1[nt];
      lsq[r][nt * 16 + c0] = pq1[nt];
    }
    __syncthreads();
    if (tid < HD) {
      float s = 0.0f, q = 0.0f;
#pragma unroll
      for (int r2 = 0; r2 < 16; ++r2) { s += lsum[r2][tid]; q += lsq[r2][tid]; }
      atomicAdd(gs + (sg0 + 1) * HD + tid, s);
      atomicAdd(gq + (sg0 + 1) * HD + tid, q);
    }
    if (tid == 0) {
      int n0 = 0;
      for (int r2 = 0; r2 < nvalid; ++r2) n0 += (ridx[r2] == 0);
      atomicAdd(gc + sg0, (float)n0);
      atomicAdd(gc + sg0 + 1, (float)(nvalid - n0));
    }
  } else {
#pragma unroll
    for (int j = 0; j < 4; ++j) {
      int rb = wave * 16 + kg * 4 + j;
      int n = base0 + rb;
      if (n >= NN) break;
      unsigned short* orow = obf + (size_t)n * HD;
      int g = sg0 + ridx[rb];
#pragma unroll
      for (int nt = 0; nt < 8; ++nt) {
        float v = acc[nt][j] + bv[nt];
        orow[nt * 16 + c0] = f2bf(v);
        atomicAdd(gs + g * HD + nt * 16 + c0, v);
        atomicAdd(gq + g * HD + nt * 16 + c0, v * v);
      }
    }
    if (tid < nvalid) atomicAdd(gc + batch[base0 + tid], 1.0f);
  }
}

// reduce 8 shard partials -> mean, rstd
__global__ __launch_bounds__(256) void finalize_k(const float* __restrict__ gsumS,
    const float* __restrict__ gsqS, const float* __restrict__ gcntS,
    const float* __restrict__ alpha, float* __restrict__ mean,
    float* __restrict__ rstd) {
  int i = blockIdx.x * 256 + threadIdx.x;
  if (i >= NG * HD) return;
  int g = i >> 7, d = i & 127;
  float s = 0.0f, q = 0.0f, cnt = 0.0f;
#pragma unroll
  for (int sh = 0; sh < NSH; ++sh) {
    s += gsumS[sh * (NG * HD) + i];
    q += gsqS[sh * (NG * HD) + i];
    cnt += gcntS[sh * NG + g];
  }
  cnt = fmaxf(cnt, 1.0f);
  float mu = s / cnt;
  float a = alpha[d];
  float var = q / cnt - mu * mu * (2.0f * a - a * a);
  mean[i] = mu;
  rstd[i] = rsqrtf(fmaxf(var, 0.0f) + GN_EPS);
}

// norm + GELU + residual: reads bf16 obf + f32 x, writes f32 d_out
__global__ __launch_bounds__(256) void final_k(const unsigned short* __restrict__ obf,
    float* __restrict__ out, const float* __restrict__ x,
    const int* __restrict__ batch, const float* __restrict__ mean,
    const float* __restrict__ rstd, const float* __restrict__ alpha,
    const float* __restrict__ gw, const float* __restrict__ gb) {
  size_t i = ((size_t)blockIdx.x * 256 + threadIdx.x) * 4;
  if (i >= (size_t)NN * HD) return;
  int n = (int)(i >> 7);
  int d = (int)(i & 127);
  int g = batch[n];
  uint2 ov = *(const uint2*)(obf + i);
  float4 xv = *(const float4*)(x + i);
  float4 al = *(const float4*)(alpha + d);
  float4 w  = *(const float4*)(gw + d);
  float4 b  = *(const float4*)(gb + d);
  float4 mn = *(const float4*)(mean + (size_t)g * HD + d);
  float4 rs = *(const float4*)(rstd + (size_t)g * HD + d);
  float vv[4] = {bf_lo(ov.x), bf_hi(ov.x), bf_lo(ov.y), bf_hi(ov.y)};
  float xx[4] = {xv.x, xv.y, xv.z, xv.w};
  float aa[4] = {al.x, al.y, al.z, al.w};
  float ww[4] = {w.x, w.y, w.z, w.w};
  float bb2[4] = {b.x, b.y, b.z, b.w};
  float mm[4] = {mn.x, mn.y, mn.z, mn.w};
  float rr[4] = {rs.x, rs.y, rs.z, rs.w};
  float r[4];
#pragma unroll
  for (int c = 0; c < 4; ++c) {
    float sub = vv[c] - aa[c] * mm[c];
    float nm  = ww[c] * sub * rr[c] + bb2[c];
    float ge  = 0.5f * nm * (1.0f + erff(nm * 0.70710678118654752f));
    r[c] = ge + xx[c];
  }
  float4 res = {r[0], r[1], r[2], r[3]};
  *(float4*)(out + i) = res;
}

extern "C" void kernel_launch(void* const* d_in, const int* in_sizes, int n_in,
                              void* d_out, int out_size, void* d_ws, size_t ws_size,
                              hipStream_t stream) {
  const float* x     = (const float*)d_in[0];
  const int*   ei    = (const int*)d_in[1];
  const int*   batch = (const int*)d_in[2];
  const float* Wl    = (const float*)d_in[3];
  const float* bl    = (const float*)d_in[4];
  const float* Wr    = (const float*)d_in[5];
  const float* gw    = (const float*)d_in[6];
  const float* gb    = (const float*)d_in[7];
  const float* alpha = (const float*)d_in[8];

  float* out = (float*)d_out;
  int*   wsi = (int*)d_ws;
  float* wsf = (float*)d_ws;
  int* rowptr = wsi + ROWPTR_OFF;
  int* bb     = wsi + BB_OFF;
  int* cs     = wsi + CS_OFF;
  float* gsumS = wsf + GSUMS_OFF;
  float* gsqS  = wsf + GSQS_OFF;
  float* gcntS = wsf + GCNTS_OFF;
  float* mean  = wsf + MEAN_OFF;
  float* rstd  = wsf + RSTD_OFF;
  unsigned short* srcs  = (unsigned short*)(wsi + SRCS_OFF);
  unsigned short* psrc  = (unsigned short*)(wsi + PSRC_OFF);
  unsigned char*  pdlow = (unsigned char*)(wsi + PDLOW_OFF);
  unsigned short* wpack = (unsigned short*)(wsi + WPACK_OFF);
  unsigned short* xb    = (unsigned short*)(wsi + XB_OFF);
  unsigned short* aggb  = (unsigned short*)(wsi + AGGB_OFF);
  unsigned short* obf   = (unsigned short*)(wsi + OBF_OFF);

  prep_rhist_k<<<PREP_BLKS + NBLK_R, 256, 0, stream>>>(
      x, Wl, Wr, xb, wpack, (int*)(wsf + GSUMS_OFF), ei, bb);

  csum_k<<<NCHS, 256, 0, stream>>>(bb, cs);
  cfill_k<<<(NBB + 1023) / 1024, 1024, 0, stream>>>(bb, cs);
  rscatter_k<<<NBLK_R, 256, 0, stream>>>(ei, bb, psrc, pdlow);
  rfinal_k<<<NBUCK, 256, 0, stream>>>(bb, psrc, pdlow, srcs, rowptr);

  gather_k<<<(NN * 16 + 255) / 256, 256, 0, stream>>>(rowptr, srcs, xb, aggb);

  gemm_k<<<(NN + 63) / 64, 256, 0, stream>>>(aggb, xb, wpack, bl, batch, obf,
                                             gsumS, gsqS, gcntS);

  finalize_k<<<16, 256, 0, stream>>>(gsumS, gsqS, gcntS, alpha, mean, rstd);

  final_k<<<(NN * HD / 4 + 255) / 256, 256, 0, stream>>>(
      obf, out, x, batch, mean, rstd, alpha, gw, gb);
}